// Round 21
// baseline (345.996 us; speedup 1.0000x reference)
//
#include <hip/hip_runtime.h>
#include <hip/hip_bf16.h>

#define L 2048
#define D 1024
#define NH 16
#define HD 64
#define SPLIT 4
#define JCH (L / SPLIT)
#define LOG2E 1.4426950408889634f

typedef __attribute__((ext_vector_type(8))) short bf16x8;
typedef __attribute__((ext_vector_type(4))) float f32x4;

#define MFMA(a, b, c) __builtin_amdgcn_mfma_f32_16x16x32_bf16(a, b, c, 0, 0, 0)

__device__ __forceinline__ short f2bf(float x) {
  __hip_bfloat16 h = __float2bfloat16(x);
  return *reinterpret_cast<short*>(&h);
}

// async global->LDS, 16B per lane. LDS dest = wave-uniform base + lane*16.
__device__ __forceinline__ void gll16(const void* g, void* l) {
  __builtin_amdgcn_global_load_lds(
      (const __attribute__((address_space(1))) void*)(uintptr_t)g,
      (__attribute__((address_space(3))) void*)(unsigned)(uintptr_t)l, 16, 0, 0);
}

// ---------------------------------------------------------------- prep: trig table + all f32->bf16 casts
__global__ void prep_kernel(const float* __restrict__ q,
                            const float* __restrict__ w0, const float* __restrict__ w1,
                            const float* __restrict__ w2, const float* __restrict__ w3,
                            float* __restrict__ costab, float* __restrict__ sintab,
                            short* __restrict__ dq, short* __restrict__ d0,
                            short* __restrict__ d1, short* __restrict__ d2,
                            short* __restrict__ d3) {
  int i = blockIdx.x * 256 + threadIdx.x;  // 65536 trig + 524288 q4 + 4*262144 w4
  if (i < 65536) {
    int t = i >> 5, fi = i & 31;
    float f = exp2f(-(float)fi * (13.287712379549449f / 32.0f));  // 10000^(-fi/32)
    float ang = (float)t * f;
    costab[i] = cosf(ang);
    sintab[i] = sinf(ang);
    return;
  }
  int i2 = i - 65536;
  const float* src;
  short* dst;
  int off;
  if (i2 < L * D / 4) {
    src = q; dst = dq; off = i2;
  } else {
    int j = i2 - L * D / 4;
    int seg = j >> 18;          // D*D/4 = 262144 = 2^18
    off = j & (262144 - 1);
    src = seg == 0 ? w0 : seg == 1 ? w1 : seg == 2 ? w2 : w3;
    dst = seg == 0 ? d0 : seg == 1 ? d1 : seg == 2 ? d2 : d3;
  }
  float4 v = ((const float4*)src)[off];
  short4 o;
  o.x = f2bf(v.x); o.y = f2bf(v.y); o.z = f2bf(v.z); o.w = f2bf(v.w);
  ((short4*)dst)[off] = o;
}

// ---------------------------------------------------------------- fused q/k/v projection (128x64 tile)
// grid (D/64, L/128, 3). Wave = 32 rows x 64 cols (RoPE d<->d+-32 pairing in-wave).
// mode 0: q -> Qs, QR scaled 0.125*LOG2E; 1: k; 2: v (transposed)
__global__ __launch_bounds__(256) void proj3_kernel(
    const short* __restrict__ X,
    const short* __restrict__ Wq, const short* __restrict__ Wk, const short* __restrict__ Wv,
    const float* __restrict__ bq, const float* __restrict__ bk, const float* __restrict__ bv,
    const float* __restrict__ costab, const float* __restrict__ sintab,
    short* __restrict__ Qs, short* __restrict__ QRb, short* __restrict__ Kbb,
    short* __restrict__ KRb, short* __restrict__ Vt) {
  int mode = blockIdx.z;
  const short* W = mode == 0 ? Wq : (mode == 1 ? Wk : Wv);
  const float* bias = mode == 0 ? bq : (mode == 1 ? bk : bv);
  short* out_main = mode == 0 ? Qs : (mode == 1 ? Kbb : Vt);
  short* out_rope = mode == 0 ? QRb : KRb;

  int w = threadIdx.x >> 6, lane = threadIdx.x & 63;
  int c = lane & 15, g = lane >> 4;
  int wi0 = blockIdx.y * 128 + w * 32;
  int wj0 = blockIdx.x * 64;

  f32x4 acc[2][4];
#pragma unroll
  for (int m = 0; m < 2; ++m)
#pragma unroll
    for (int n = 0; n < 4; ++n) acc[m][n] = (f32x4){0.f, 0.f, 0.f, 0.f};

  for (int k0 = 0; k0 < D; k0 += 32) {
    bf16x8 aF[2], bF[4];
#pragma unroll
    for (int m = 0; m < 2; ++m)
      aF[m] = *(const bf16x8*)(X + (size_t)(wi0 + m * 16 + c) * D + k0 + g * 8);
#pragma unroll
    for (int n = 0; n < 4; ++n)
      bF[n] = *(const bf16x8*)(W + (size_t)(wj0 + n * 16 + c) * D + k0 + g * 8);
#pragma unroll
    for (int m = 0; m < 2; ++m)
#pragma unroll
      for (int n = 0; n < 4; ++n) acc[m][n] = MFMA(aF[m], bF[n], acc[m][n]);
  }

  float scale = (mode == 0) ? 0.125f * LOG2E : 1.0f;
#pragma unroll
  for (int m = 0; m < 2; ++m) {
#pragma unroll
    for (int r = 0; r < 4; ++r) {
      int i = wi0 + m * 16 + g * 4 + r;
      float v4[4];
#pragma unroll
      for (int n = 0; n < 4; ++n)
        v4[n] = (acc[m][n][r] + bias[wj0 + n * 16 + c]) * scale;
      if (mode == 2) {
#pragma unroll
        for (int n = 0; n < 4; ++n) {
          int col = wj0 + n * 16 + c;
          out_main[(size_t)col * L + i] = f2bf(v4[n]);  // Vt[col][i]
        }
      } else {
#pragma unroll
        for (int n = 0; n < 4; ++n) {
          int col = wj0 + n * 16 + c;
          out_main[(size_t)i * D + col] = f2bf(v4[n]);
          float rot = (n < 2) ? -v4[n + 2] : v4[n - 2];
          int fidx = i * 32 + (n & 1) * 16 + c;
          float vr = v4[n] * costab[fidx] + rot * sintab[fidx];
          out_rope[(size_t)i * D + col] = f2bf(vr);
        }
      }
    }
  }
}

// ---------------------------------------------------------------- avg dual-GEMM (128x64 tile)
// grid (L/64, L/128). Wave = 64 rows x 32 cols. avg4 is LOG2E*avg (exp2 domain).
__global__ __launch_bounds__(256) void avg_kernel(
    const short* __restrict__ QR, const short* __restrict__ KR,
    const short* __restrict__ Qs, const short* __restrict__ Kb,
    const int* __restrict__ ids, f32x4* __restrict__ avg4) {
  int ib = blockIdx.y * 128, jb = blockIdx.x * 64;
  if (ids[ib] == ids[ib + 127] && ids[jb] == ids[jb + 63] && ids[ib] == ids[jb])
    return;  // all positions diagonal -> avg never consumed here

  int w = threadIdx.x >> 6, lane = threadIdx.x & 63;
  int c = lane & 15, g = lane >> 4;
  int wi0 = ib + (w >> 1) * 64;
  int wj0 = jb + (w & 1) * 32;

  f32x4 acc1[4][2], acc2[4][2];
#pragma unroll
  for (int m = 0; m < 4; ++m)
#pragma unroll
    for (int n = 0; n < 2; ++n) {
      acc1[m][n] = (f32x4){0.f, 0.f, 0.f, 0.f};
      acc2[m][n] = (f32x4){0.f, 0.f, 0.f, 0.f};
    }

  for (int k0 = 0; k0 < D; k0 += 32) {
    bf16x8 aF[4], a2F[4], bF[2], b2F[2];
#pragma unroll
    for (int m = 0; m < 4; ++m) {
      aF[m] = *(const bf16x8*)(QR + (size_t)(wi0 + m * 16 + c) * D + k0 + g * 8);
      a2F[m] = *(const bf16x8*)(Qs + (size_t)(wi0 + m * 16 + c) * D + k0 + g * 8);
    }
#pragma unroll
    for (int n = 0; n < 2; ++n) {
      bF[n] = *(const bf16x8*)(KR + (size_t)(wj0 + n * 16 + c) * D + k0 + g * 8);
      b2F[n] = *(const bf16x8*)(Kb + (size_t)(wj0 + n * 16 + c) * D + k0 + g * 8);
    }
#pragma unroll
    for (int m = 0; m < 4; ++m)
#pragma unroll
      for (int n = 0; n < 2; ++n) {
        acc1[m][n] = MFMA(aF[m], bF[n], acc1[m][n]);
        acc2[m][n] = MFMA(a2F[m], b2F[n], acc2[m][n]);
      }
  }

#pragma unroll
  for (int m = 0; m < 4; ++m)
#pragma unroll
    for (int n = 0; n < 2; ++n) {
      int j = wj0 + n * 16 + c;
      f32x4 o;
#pragma unroll
      for (int r = 0; r < 4; ++r) o[r] = (acc1[m][n][r] - acc2[m][n][r]) * 0.0625f;
      avg4[(size_t)(((wi0 + m * 16) >> 2) + g) * L + j] = o;
    }
}

// ---------------------------------------------------------------- single-pass flash, KV-split
// grid (L/64, NH, SPLIT). T4 counted-vmcnt pipeline: per-iter issue order is
// V(8) -> A-prefetch(8) -> G-staging(4, LAST); s_waitcnt vmcnt(20) guarantees
// tile-t staging complete while leaving next staging + V in flight; raw
// s_barriers (no vmcnt0 drain). Wrap prefetches keep count uniform. LDS 40960.
__global__ __launch_bounds__(256) void flash3_kernel(
    const short* __restrict__ Qs, const short* __restrict__ Kb,
    const short* __restrict__ QR, const short* __restrict__ KR,
    const short* __restrict__ Vt, const f32x4* __restrict__ avg4,
    const int* __restrict__ ids, float* __restrict__ m_part,
    float* __restrict__ l_part, float* __restrict__ acc_part) {
  int h = blockIdx.y, sp = blockIdx.z;
  int w = threadIdx.x >> 6, lane = threadIdx.x & 63;
  int c = lane & 15, g = lane >> 4;
  int i0 = blockIdx.x * 64 + w * 16;
  int hk = h * 64;

  __shared__ short kb_lds[2][64 * 64];
  __shared__ short kr_lds[2][64 * 64];
  __shared__ short plds[4][16][64];  // [wave][row][col ^ ((row&7)<<3)]

  int srow = lane >> 3;
  int sxor = (lane & 7) ^ srow;
  int r0a = w * 16, r0b = w * 16 + 8;

  bf16x8 qA[2], qrA[2];
  {
    const short* qp = Qs + (size_t)(i0 + c) * D + hk + g * 8;
    const short* qrp = QR + (size_t)(i0 + c) * D + hk + g * 8;
    qA[0] = *(const bf16x8*)qp;   qA[1] = *(const bf16x8*)(qp + 32);
    qrA[0] = *(const bf16x8*)qrp; qrA[1] = *(const bf16x8*)(qrp + 32);
  }

  int idi[4];
  float mrun[4], lsum[4];
  f32x4 acc[4];
#pragma unroll
  for (int r = 0; r < 4; ++r) {
    idi[r] = ids[i0 + g * 4 + r];
    mrun[r] = -3.0e38f;
    lsum[r] = 0.f;
  }
#pragma unroll
  for (int n = 0; n < 4; ++n) acc[n] = (f32x4){0.f, 0.f, 0.f, 0.f};

  // wave-uniform i-segment test (ids sorted)
  int ifirst = __shfl(idi[0], 0);
  bool iu = __all((idi[0] == idi[1]) & (idi[1] == idi[2]) & (idi[2] == idi[3]) &
                  (idi[0] == ifirst));

  const f32x4* avrow = avg4 + (size_t)((i0 >> 2) + g) * L;
  int jbase = sp * JCH;
  const int NT = JCH / 64;

  // prologue: A(0) prefetch, then G(0) staging LAST (vmcnt accounting)
  f32x4 avn[4];
  int idjn[4];
#pragma unroll
  for (int sub = 0; sub < 4; ++sub) {
    avn[sub] = avrow[jbase + sub * 16 + c];
    idjn[sub] = ids[jbase + sub * 16 + c];
  }
  gll16(Kb + (size_t)(jbase + r0a + srow) * D + hk + sxor * 8, &kb_lds[0][r0a * 64]);
  gll16(Kb + (size_t)(jbase + r0b + srow) * D + hk + sxor * 8, &kb_lds[0][r0b * 64]);
  gll16(KR + (size_t)(jbase + r0a + srow) * D + hk + sxor * 8, &kr_lds[0][r0a * 64]);
  gll16(KR + (size_t)(jbase + r0b + srow) * D + hk + sxor * 8, &kr_lds[0][r0b * 64]);

  int cur = 0;
  for (int jt = 0; jt < NT; ++jt) {
    int jb = jbase + jt * 64;
    int jn = (jt + 1 < NT) ? jb + 64 : jbase;  // wrap: keeps issue count uniform

    // V(t): 8 loads (consumed at PV; compiler waits vmcnt before PV use)
    bf16x8 vf0[4], vf1[4];
#pragma unroll
    for (int n = 0; n < 4; ++n) {
      const short* vp = Vt + (size_t)(hk + n * 16 + c) * L + jb + g * 8;
      vf0[n] = *(const bf16x8*)vp;
      vf1[n] = *(const bf16x8*)(vp + 32);
    }

    // rotate A(t) (compiler inserts counted wait; G(t) stays in flight)
    f32x4 av[4];
    int idj[4];
#pragma unroll
    for (int sub = 0; sub < 4; ++sub) { av[sub] = avn[sub]; idj[sub] = idjn[sub]; }

    // A(t+1): 8 loads
#pragma unroll
    for (int sub = 0; sub < 4; ++sub) {
      avn[sub] = avrow[jn + sub * 16 + c];
      idjn[sub] = ids[jn + sub * 16 + c];
    }

    // G(t+1): 4 gll16 into the other buffer (issued LAST)
    {
      short* kd = &kb_lds[cur ^ 1][0];
      short* rd = &kr_lds[cur ^ 1][0];
      gll16(Kb + (size_t)(jn + r0a + srow) * D + hk + sxor * 8, kd + r0a * 64);
      gll16(Kb + (size_t)(jn + r0b + srow) * D + hk + sxor * 8, kd + r0b * 64);
      gll16(KR + (size_t)(jn + r0a + srow) * D + hk + sxor * 8, rd + r0a * 64);
      gll16(KR + (size_t)(jn + r0b + srow) * D + hk + sxor * 8, rd + r0b * 64);
    }

    // counted wait: 20 ops issued after G(t) (V8 + A8 + G4) -> G(t) complete;
    // G(t+1)/A(t+1)/V(t) stay in flight across the barrier.
    asm volatile("s_waitcnt vmcnt(20)" ::: "memory");
    __builtin_amdgcn_sched_barrier(0);
    __builtin_amdgcn_s_barrier();

    // wave-uniform j-segment test
    int jfirst = __shfl(idj[0], 0);
    bool ju = __all((idj[0] == idj[1]) & (idj[1] == idj[2]) & (idj[2] == idj[3]) &
                    (idj[0] == jfirst));

    const short* kbb = &kb_lds[cur][c * 64];
    const short* krb = &kr_lds[cur][c * 64];
    int co0 = (g ^ (c & 7)) * 8;
    int co1 = ((4 + g) ^ (c & 7)) * 8;

    float t[4][4];
    if (iu && ju && ifirst == jfirst) {
      // pure diagonal: rpe only
#pragma unroll
      for (int sub = 0; sub < 4; ++sub) {
        bf16x8 kr0 = *(const bf16x8*)(krb + sub * 1024 + co0);
        bf16x8 kr1 = *(const bf16x8*)(krb + sub * 1024 + co1);
        f32x4 z = (f32x4){0.f, 0.f, 0.f, 0.f};
        f32x4 rp = MFMA(qrA[1], kr1, MFMA(qrA[0], kr0, z));
#pragma unroll
        for (int r = 0; r < 4; ++r) t[sub][r] = rp[r];
      }
    } else if (iu && ju) {
      // pure off-diagonal: raw + avg only
#pragma unroll
      for (int sub = 0; sub < 4; ++sub) {
        bf16x8 k0 = *(const bf16x8*)(kbb + sub * 1024 + co0);
        bf16x8 k1 = *(const bf16x8*)(kbb + sub * 1024 + co1);
        f32x4 z = (f32x4){0.f, 0.f, 0.f, 0.f};
        f32x4 rw = MFMA(qA[1], k1, MFMA(qA[0], k0, z));
#pragma unroll
        for (int r = 0; r < 4; ++r) t[sub][r] = rw[r] + av[sub][r];
      }
    } else {
      // mixed tile: full path
#pragma unroll
      for (int sub = 0; sub < 4; ++sub) {
        bf16x8 k0 = *(const bf16x8*)(kbb + sub * 1024 + co0);
        bf16x8 k1 = *(const bf16x8*)(kbb + sub * 1024 + co1);
        bf16x8 kr0 = *(const bf16x8*)(krb + sub * 1024 + co0);
        bf16x8 kr1 = *(const bf16x8*)(krb + sub * 1024 + co1);
        f32x4 z = (f32x4){0.f, 0.f, 0.f, 0.f};
        f32x4 rw = MFMA(qA[1], k1, MFMA(qA[0], k0, z));
        f32x4 rp = MFMA(qrA[1], kr1, MFMA(qrA[0], kr0, z));
#pragma unroll
        for (int r = 0; r < 4; ++r)
          t[sub][r] = (idi[r] == idj[sub]) ? rp[r] : (rw[r] + av[sub][r]);
      }
    }

    // defer-max
    float tm[4];
#pragma unroll
    for (int r = 0; r < 4; ++r)
      tm[r] = fmaxf(fmaxf(t[0][r], t[1][r]), fmaxf(t[2][r], t[3][r]));
    bool ok = (tm[0] <= mrun[0] + 8.f) && (tm[1] <= mrun[1] + 8.f) &&
              (tm[2] <= mrun[2] + 8.f) && (tm[3] <= mrun[3] + 8.f);
    if (!__all(ok)) {
#pragma unroll
      for (int r = 0; r < 4; ++r) {
        float m2 = tm[r];
#pragma unroll
        for (int d = 1; d < 16; d <<= 1) m2 = fmaxf(m2, __shfl_xor(m2, d));
        float mn = fmaxf(mrun[r], m2);
        float so = exp2f(mrun[r] - mn);
        mrun[r] = mn;
        lsum[r] *= so;
#pragma unroll
        for (int n = 0; n < 4; ++n) acc[n][r] *= so;
      }
    }

    // p = exp2(t - m) -> swizzled plds (wave-private tile)
#pragma unroll
    for (int sub = 0; sub < 4; ++sub)
#pragma unroll
      for (int r = 0; r < 4; ++r) {
        float p = exp2f(t[sub][r] - mrun[r]);
        lsum[r] += p;
        int prow = g * 4 + r;
        plds[w][prow][(sub * 16 + c) ^ ((prow & 7) << 3)] = f2bf(p);
      }

    // PV with swizzled reads
    {
      int pc0 = (g * 8) ^ ((c & 7) << 3);
      int pc1 = (32 + g * 8) ^ ((c & 7) << 3);
      bf16x8 pa = *(const bf16x8*)(&plds[w][c][pc0]);
#pragma unroll
      for (int n = 0; n < 4; ++n) acc[n] = MFMA(pa, vf0[n], acc[n]);
      bf16x8 pb = *(const bf16x8*)(&plds[w][c][pc1]);
#pragma unroll
      for (int n = 0; n < 4; ++n) acc[n] = MFMA(pb, vf1[n], acc[n]);
    }

    // end barrier (raw, NO vmcnt drain): guards buf swap; max 1-iter skew
    asm volatile("" ::: "memory");
    __builtin_amdgcn_s_barrier();
    cur ^= 1;
  }

#pragma unroll
  for (int r = 0; r < 4; ++r) {
#pragma unroll
    for (int d = 1; d < 16; d <<= 1) lsum[r] += __shfl_xor(lsum[r], d);
  }
  size_t sb = (size_t)(sp * NH + h) * L;
  if (c == 0) {
#pragma unroll
    for (int r = 0; r < 4; ++r) {
      m_part[sb + i0 + g * 4 + r] = mrun[r];
      l_part[sb + i0 + g * 4 + r] = lsum[r];
    }
  }
#pragma unroll
  for (int n = 0; n < 4; ++n)
#pragma unroll
    for (int r = 0; r < 4; ++r)
      acc_part[(sb + i0 + g * 4 + r) * HD + n * 16 + c] = acc[n][r];
}

// ---------------------------------------------------------------- merge partials
__global__ void merge_kernel(const float* __restrict__ m_part,
                             const float* __restrict__ l_part,
                             const float* __restrict__ acc_part,
                             float* __restrict__ mfin, float* __restrict__ lfin,
                             short* __restrict__ attn_bf) {
  int idx = blockIdx.x * 256 + threadIdx.x;  // NH*L*HD
  int d = idx & (HD - 1);
  int hi = idx >> 6;          // h*L + i
  int i = hi & (L - 1), h = hi >> 11;
  float m4 = -3.0e38f;
#pragma unroll
  for (int s = 0; s < SPLIT; ++s)
    m4 = fmaxf(m4, m_part[(size_t)(s * NH + h) * L + i]);
  float l = 0.f, o = 0.f;
#pragma unroll
  for (int s = 0; s < SPLIT; ++s) {
    size_t sb = (size_t)(s * NH + h) * L + i;
    float e = exp2f(m_part[sb] - m4);
    l += l_part[sb] * e;
    o += acc_part[sb * HD + d] * e;
  }
  attn_bf[(size_t)i * D + h * HD + d] = f2bf(o / l);
  if (d == 0) { mfin[h * L + i] = m4; lfin[h * L + i] = l; }
}

// ---------------------------------------------------------------- probs mean + out proj (fused launch)
// grid 1536 blocks 1D: [0,1024) pavg body (32x32 j,i blocks); [1024,1536) outproj.
__global__ __launch_bounds__(256) void pavgout_kernel(
    const short* __restrict__ Qs, const short* __restrict__ Kb,
    const short* __restrict__ QR, const short* __restrict__ KR,
    const f32x4* __restrict__ avg4, const int* __restrict__ ids,
    const float* __restrict__ m_ws, const float* __restrict__ l_ws,
    float* __restrict__ out1,
    const short* __restrict__ A, const short* __restrict__ W,
    const float* __restrict__ bias, float* __restrict__ out0) {
  __shared__ short kb_lds[2][64 * 64];
  __shared__ short kr_lds[2][64 * 64];
  __shared__ float mS[NH][64], lS[NH][64];

  int bid = blockIdx.x;
  int w = threadIdx.x >> 6, lane = threadIdx.x & 63;
  int c = lane & 15, g = lane >> 4;

  if (bid >= 1024) {
    // ---------------- out proj body (64x64 tile) ----------------
    int idx = bid - 1024;
    int wj0 = (idx & 15) * 64 + (w & 1) * 32;
    int wi0 = (idx >> 4) * 64 + (w >> 1) * 32;

    f32x4 acc[2][2];
#pragma unroll
    for (int m = 0; m < 2; ++m)
#pragma unroll
      for (int n = 0; n < 2; ++n) acc[m][n] = (f32x4){0.f, 0.f, 0.f, 0.f};

    for (int k0 = 0; k0 < D; k0 += 32) {
      bf16x8 aF[2], bF[2];
#pragma unroll
      for (int m = 0; m < 2; ++m)
        aF[m] = *(const bf16x8*)(A + (size_t)(wi0 + m * 16 + c) * D + k0 + g * 8);
#pragma unroll
      for (int n = 0; n < 2; ++n)
        bF[n] = *(const bf16x8*)(W + (size_t)(wj0 + n * 16 + c) * D + k0 + g * 8);
#pragma unroll
      for (int m = 0; m < 2; ++m)
#pragma unroll
        for (int n = 0; n < 2; ++n) acc[m][n] = MFMA(aF[m], bF[n], acc[m][n]);
    }

#pragma unroll
    for (int m = 0; m < 2; ++m)
#pragma unroll
      for (int n = 0; n < 2; ++n)
#pragma unroll
        for (int r = 0; r < 4; ++r) {
          int i = wi0 + m * 16 + g * 4 + r;
          int col = wj0 + n * 16 + c;
          out0[(size_t)i * D + col] = acc[m][n][r] + bias[col];
        }
    return;
  }

  // ---------------- pavg body ----------------
  int j0 = (bid & 31) * 64;
  int iblk = (bid >> 5) * 64;
  int i0 = iblk + w * 16;

  int srow = lane >> 3;
  int sxor = (lane & 7) ^ srow;
  int r0a = w * 16, r0b = w * 16 + 8;

  // block-constant segment mode (wave-uniform scalar loads; ids sorted)
  int si0 = ids[iblk], si1 = ids[iblk + 63];
  int sj0 = ids[j0], sj1 = ids[j0 + 63];
  int mode = (si0 == si1 && sj0 == sj1) ? ((si0 == sj0) ? 0 : 1) : 2;

  for (int idx = threadIdx.x; idx < NH * 64; idx += 256) {
    int hh = idx >> 6, rr = idx & 63;
    mS[hh][rr] = m_ws[hh * L + iblk + rr];
    lS[hh][rr] = 1.0f / l_ws[hh * L + iblk + rr];
  }

  // stage head 0 (skip the unneeded array when mode is uniform)
  if (mode != 0) {
    gll16(Kb + (size_t)(j0 + r0a + srow) * D + sxor * 8, &kb_lds[0][r0a * 64]);
    gll16(Kb + (size_t)(j0 + r0b + srow) * D + sxor * 8, &kb_lds[0][r0b * 64]);
  }
  if (mode != 1) {
    gll16(KR + (size_t)(j0 + r0a + srow) * D + sxor * 8, &kr_lds[0][r0a * 64]);
    gll16(KR + (size_t)(j0 + r0b + srow) * D + sxor * 8, &kr_lds[0][r0b * 64]);
  }

  int idi[4], idj[4];
  f32x4 av[4];
  {
    const f32x4* avrow = avg4 + (size_t)((i0 >> 2) + g) * L;
#pragma unroll
    for (int sub = 0; sub < 4; ++sub) {
      av[sub] = avrow[j0 + sub * 16 + c];
      idj[sub] = ids[j0 + sub * 16 + c];
    }
#pragma unroll
    for (int r = 0; r < 4; ++r) idi[r] = ids[i0 + g * 4 + r];
  }

  f32x4 psum[4];
#pragma unroll
  for (int sub = 0; sub < 4; ++sub) psum[sub] = (f32x4){0.f, 0.f, 0.f, 0.f};

  const short* qbase = Qs + (size_t)(i0 + c) * D + g * 8;
  const short* qrbase = QR + (size_t)(i0 + c) * D + g * 8;

  bf16x8 nq0, nq1, nqr0, nqr1;
  if (mode != 0) { nq0 = *(const bf16x8*)qbase; nq1 = *(const bf16x8*)(qbase + 32); }
  if (mode != 1) { nqr0 = *(const bf16x8*)qrbase; nqr1 = *(const bf16x8*)(qrbase + 32); }

  __syncthreads();

  int cur = 0;
#pragma unroll 1
  for (int hh = 0; hh < NH; ++hh) {
    if (hh + 1 < NH) {
      int hkn = (hh + 1) * 64;
      short* kd = &kb_lds[cur ^ 1][0];
      short* rd = &kr_lds[cur ^ 1][0];
      if (mode != 0) {
        gll16(Kb + (size_t)(j0 + r0a + srow) * D + hkn + sxor * 8, kd + r0a * 64);
        gll16(Kb + (size_t)(j0 + r0b + srow) * D + hkn + sxor * 8, kd + r0b * 64);
      }
      if (mode != 1) {
        gll16(KR + (size_t)(j0 + r0a + srow) * D + hkn + sxor * 8, rd + r0a * 64);
        gll16(KR + (size_t)(j0 + r0b + srow) * D + hkn + sxor * 8, rd + r0b * 64);
      }
    }

    bf16x8 q0 = nq0, q1 = nq1, qr0 = nqr0, qr1 = nqr1;
    if (hh + 1 < NH) {
      int hkn = (hh + 1) * 64;
      if (mode != 0) {
        nq0 = *(const bf16x8*)(qbase + hkn);
        nq1 = *(const bf16x8*)(qbase + hkn + 32);
      }
      if (mode != 1) {
        nqr0 = *(const bf16x8*)(qrbase + hkn);
        nqr1 = *(const bf16x8*)(qrbase + hkn + 32);
      }
    }

    const short* kbb = &kb_lds[cur][c * 64];
    const short* krb = &kr_lds[cur][c * 64];
    int co0 = (g ^ (c & 7)) * 8;
    int co1 = ((4 + g) ^ (c & 7)) * 8;

    f32x4 m4 = *(const f32x4*)(&mS[hh][w * 16 + g * 4]);
    f32x4 l4 = *(const f32x4*)(&lS[hh][w * 16 + g * 4]);

    if (mode == 0) {
#pragma unroll
      for (int sub = 0; sub < 4; ++sub) {
        bf16x8 kr0 = *(const bf16x8*)(krb + sub * 1024 + co0);
        bf16x8 kr1 = *(const bf16x8*)(krb + sub * 1024 + co1);
        f32x4 z = (f32x4){0.f, 0.f, 0.f, 0.f};
        f32x4 rp = MFMA(qr1, kr1, MFMA(qr0, kr0, z));
#pragma unroll
        for (int r = 0; r < 4; ++r)
          psum[sub][r] += exp2f(rp[r] - m4[r]) * l4[r];
      }
    } else if (mode == 1) {
#pragma unroll
      for (int sub = 0; sub < 4; ++sub) {
        bf16x8 k0 = *(const bf16x8*)(kbb + sub * 1024 + co0);
        bf16x8 k1 = *(const bf16x8*)(kbb + sub * 1024 + co1);
        f32x4 z = (f32x4){0.f, 0.f, 0.f, 0.f};
        f32x4 rw = MFMA(q1, k1, MFMA(q0, k0, z));
#pragma unroll
        for (int r = 0; r < 4; ++r)
          psum[sub][r] += exp2f(rw[r] + av[sub][r] - m4[r]) * l4[r];
      }
    } else {
#pragma unroll
      for (int sub = 0; sub < 4; ++sub) {
        bf16x8 k0 = *(const bf16x8*)(kbb + sub * 1024 + co0);
        bf16x8 k1 = *(const bf16x8*)(kbb + sub * 1024 + co1);
        bf16x8 kr0 = *(const bf16x8*)(krb + sub * 1024 + co0);
        bf16x8 kr1 = *(const bf16x8*)(krb + sub * 1024 + co1);
        f32x4 z = (f32x4){0.f, 0.f, 0.f, 0.f};
        f32x4 rw = MFMA(q1, k1, MFMA(q0, k0, z));
        f32x4 rp = MFMA(qr1, kr1, MFMA(qr0, kr0, z));
#pragma unroll
        for (int r = 0; r < 4; ++r) {
          float s = (idi[r] == idj[sub]) ? rp[r] : (rw[r] + av[sub][r]);
          psum[sub][r] += exp2f(s - m4[r]) * l4[r];
        }
      }
    }

    __syncthreads();
    cur ^= 1;
  }

#pragma unroll
  for (int sub = 0; sub < 4; ++sub)
#pragma unroll
    for (int r = 0; r < 4; ++r)
      out1[(size_t)(i0 + g * 4 + r) * L + j0 + sub * 16 + c] = psum[sub][r] * 0.0625f;
}

// ---------------------------------------------------------------- launch
extern "C" void kernel_launch(void* const* d_in, const int* in_sizes, int n_in,
                              void* d_out, int out_size, void* d_ws, size_t ws_size,
                              hipStream_t stream) {
  const float* query = (const float*)d_in[0];
  const int* ids = (const int*)d_in[1];
  const float* wq = (const float*)d_in[2];
  const float* bq = (const float*)d_in[3];
  const float* wk = (const float*)d_in[4];
  const float* bk = (const float*)d_in[5];
  const float* wv = (const float*)d_in[6];
  const float* bv = (const float*)d_in[7];
  const float* wo = (const float*)d_in[8];
  const float* bo = (const float*)d_in[9];

  char* p = (char*)d_ws;
  auto carve = [&](size_t bytes) {
    char* r = p;
    p += (bytes + 255) & ~(size_t)255;
    return r;
  };
  short* Xbf = (short*)carve((size_t)L * D * 2);
  short* Wqb = (short*)carve((size_t)D * D * 2);
  short* Wkb = (short*)carve((size_t)D * D * 2);
  short* Wvb = (short*)carve((size_t)D * D * 2);
  short* Wob = (short*)carve((size_t)D * D * 2);
  short* Qs = (short*)carve((size_t)L * D * 2);
  short* QRb = (short*)carve((size_t)L * D * 2);
  short* Kbb = (short*)carve((size_t)L * D * 2);
  short* KRb = (short*)carve((size_t)L * D * 2);
  short* Vt = (short*)carve((size_t)L * D * 2);
  f32x4* avg4 = (f32x4*)carve((size_t)L * L * 4);
  float* m_ws = (float*)carve((size_t)NH * L * 4);
  float* l_ws = (float*)carve((size_t)NH * L * 4);
  short* attn_bf = (short*)carve((size_t)L * D * 2);
  float* costab = (float*)carve((size_t)L * 32 * 4);
  float* sintab = (float*)carve((size_t)L * 32 * 4);
  float* m_part = (float*)carve((size_t)SPLIT * NH * L * 4);
  float* l_part = (float*)carve((size_t)SPLIT * NH * L * 4);
  float* acc_part = (float*)carve((size_t)SPLIT * NH * L * HD * 4);

  float* out0 = (float*)d_out;                  // (L, 1, D)
  float* out1 = out0 + (size_t)L * D;           // (1, L, L)

  prep_kernel<<<(65536 + L * D / 4 + 4 * (D * D / 4)) / 256, 256, 0, stream>>>(
      query, wq, wk, wv, wo, costab, sintab, Xbf, Wqb, Wkb, Wvb, Wob);

  proj3_kernel<<<dim3(D / 64, L / 128, 3), 256, 0, stream>>>(
      Xbf, Wqb, Wkb, Wvb, bq, bk, bv, costab, sintab, Qs, QRb, Kbb, KRb, Vt);

  avg_kernel<<<dim3(L / 64, L / 128), 256, 0, stream>>>(QRb, KRb, Qs, Kbb, ids, avg4);

  flash3_kernel<<<dim3(L / 64, NH, SPLIT), 256, 0, stream>>>(
      Qs, Kbb, QRb, KRb, Vt, avg4, ids, m_part, l_part, acc_part);

  merge_kernel<<<(NH * L * HD) / 256, 256, 0, stream>>>(m_part, l_part, acc_part,
                                                        m_ws, l_ws, attn_bf);

  pavgout_kernel<<<1536, 256, 0, stream>>>(Qs, Kbb, QRb, KRb, avg4, ids,
                                           m_ws, l_ws, out1, attn_bf, Wob, bo, out0);
}

// Round 22
// 342.891 us; speedup vs baseline: 1.0091x; 1.0091x over previous
//
#include <hip/hip_runtime.h>
#include <hip/hip_bf16.h>

#define L 2048
#define D 1024
#define NH 16
#define HD 64
#define SPLIT 4
#define JCH (L / SPLIT)
#define LOG2E 1.4426950408889634f

typedef __attribute__((ext_vector_type(8))) short bf16x8;
typedef __attribute__((ext_vector_type(4))) float f32x4;

#define MFMA(a, b, c) __builtin_amdgcn_mfma_f32_16x16x32_bf16(a, b, c, 0, 0, 0)

__device__ __forceinline__ short f2bf(float x) {
  __hip_bfloat16 h = __float2bfloat16(x);
  return *reinterpret_cast<short*>(&h);
}

// async global->LDS, 16B per lane. LDS dest = wave-uniform base + lane*16.
__device__ __forceinline__ void gll16(const void* g, void* l) {
  __builtin_amdgcn_global_load_lds(
      (const __attribute__((address_space(1))) void*)(uintptr_t)g,
      (__attribute__((address_space(3))) void*)(unsigned)(uintptr_t)l, 16, 0, 0);
}

// ---------------------------------------------------------------- prep: trig table + all f32->bf16 casts
__global__ void prep_kernel(const float* __restrict__ q,
                            const float* __restrict__ w0, const float* __restrict__ w1,
                            const float* __restrict__ w2, const float* __restrict__ w3,
                            float* __restrict__ costab, float* __restrict__ sintab,
                            short* __restrict__ dq, short* __restrict__ d0,
                            short* __restrict__ d1, short* __restrict__ d2,
                            short* __restrict__ d3) {
  int i = blockIdx.x * 256 + threadIdx.x;  // 65536 trig + 524288 q4 + 4*262144 w4
  if (i < 65536) {
    int t = i >> 5, fi = i & 31;
    float f = exp2f(-(float)fi * (13.287712379549449f / 32.0f));  // 10000^(-fi/32)
    float ang = (float)t * f;
    costab[i] = cosf(ang);
    sintab[i] = sinf(ang);
    return;
  }
  int i2 = i - 65536;
  const float* src;
  short* dst;
  int off;
  if (i2 < L * D / 4) {
    src = q; dst = dq; off = i2;
  } else {
    int j = i2 - L * D / 4;
    int seg = j >> 18;          // D*D/4 = 262144 = 2^18
    off = j & (262144 - 1);
    src = seg == 0 ? w0 : seg == 1 ? w1 : seg == 2 ? w2 : w3;
    dst = seg == 0 ? d0 : seg == 1 ? d1 : seg == 2 ? d2 : d3;
  }
  float4 v = ((const float4*)src)[off];
  short4 o;
  o.x = f2bf(v.x); o.y = f2bf(v.y); o.z = f2bf(v.z); o.w = f2bf(v.w);
  ((short4*)dst)[off] = o;
}

// ---------------------------------------------------------------- fused q/k/v projection (128x64 tile)
// grid (D/64, L/128, 3). Wave = 32 rows x 64 cols (RoPE d<->d+-32 pairing in-wave).
// mode 0: q -> Qs, QR scaled 0.125*LOG2E; 1: k; 2: v (transposed)
__global__ __launch_bounds__(256) void proj3_kernel(
    const short* __restrict__ X,
    const short* __restrict__ Wq, const short* __restrict__ Wk, const short* __restrict__ Wv,
    const float* __restrict__ bq, const float* __restrict__ bk, const float* __restrict__ bv,
    const float* __restrict__ costab, const float* __restrict__ sintab,
    short* __restrict__ Qs, short* __restrict__ QRb, short* __restrict__ Kbb,
    short* __restrict__ KRb, short* __restrict__ Vt) {
  int mode = blockIdx.z;
  const short* W = mode == 0 ? Wq : (mode == 1 ? Wk : Wv);
  const float* bias = mode == 0 ? bq : (mode == 1 ? bk : bv);
  short* out_main = mode == 0 ? Qs : (mode == 1 ? Kbb : Vt);
  short* out_rope = mode == 0 ? QRb : KRb;

  int w = threadIdx.x >> 6, lane = threadIdx.x & 63;
  int c = lane & 15, g = lane >> 4;
  int wi0 = blockIdx.y * 128 + w * 32;
  int wj0 = blockIdx.x * 64;

  f32x4 acc[2][4];
#pragma unroll
  for (int m = 0; m < 2; ++m)
#pragma unroll
    for (int n = 0; n < 4; ++n) acc[m][n] = (f32x4){0.f, 0.f, 0.f, 0.f};

  for (int k0 = 0; k0 < D; k0 += 32) {
    bf16x8 aF[2], bF[4];
#pragma unroll
    for (int m = 0; m < 2; ++m)
      aF[m] = *(const bf16x8*)(X + (size_t)(wi0 + m * 16 + c) * D + k0 + g * 8);
#pragma unroll
    for (int n = 0; n < 4; ++n)
      bF[n] = *(const bf16x8*)(W + (size_t)(wj0 + n * 16 + c) * D + k0 + g * 8);
#pragma unroll
    for (int m = 0; m < 2; ++m)
#pragma unroll
      for (int n = 0; n < 4; ++n) acc[m][n] = MFMA(aF[m], bF[n], acc[m][n]);
  }

  float scale = (mode == 0) ? 0.125f * LOG2E : 1.0f;
#pragma unroll
  for (int m = 0; m < 2; ++m) {
#pragma unroll
    for (int r = 0; r < 4; ++r) {
      int i = wi0 + m * 16 + g * 4 + r;
      float v4[4];
#pragma unroll
      for (int n = 0; n < 4; ++n)
        v4[n] = (acc[m][n][r] + bias[wj0 + n * 16 + c]) * scale;
      if (mode == 2) {
#pragma unroll
        for (int n = 0; n < 4; ++n) {
          int col = wj0 + n * 16 + c;
          out_main[(size_t)col * L + i] = f2bf(v4[n]);  // Vt[col][i]
        }
      } else {
#pragma unroll
        for (int n = 0; n < 4; ++n) {
          int col = wj0 + n * 16 + c;
          out_main[(size_t)i * D + col] = f2bf(v4[n]);
          float rot = (n < 2) ? -v4[n + 2] : v4[n - 2];
          int fidx = i * 32 + (n & 1) * 16 + c;
          float vr = v4[n] * costab[fidx] + rot * sintab[fidx];
          out_rope[(size_t)i * D + col] = f2bf(vr);
        }
      }
    }
  }
}

// ---------------------------------------------------------------- avg dual-GEMM (128x64 tile)
// grid (L/64, L/128). Wave = 64 rows x 32 cols. avg4 is LOG2E*avg (exp2 domain).
__global__ __launch_bounds__(256) void avg_kernel(
    const short* __restrict__ QR, const short* __restrict__ KR,
    const short* __restrict__ Qs, const short* __restrict__ Kb,
    const int* __restrict__ ids, f32x4* __restrict__ avg4) {
  int ib = blockIdx.y * 128, jb = blockIdx.x * 64;
  if (ids[ib] == ids[ib + 127] && ids[jb] == ids[jb + 63] && ids[ib] == ids[jb])
    return;  // all positions diagonal -> avg never consumed here

  int w = threadIdx.x >> 6, lane = threadIdx.x & 63;
  int c = lane & 15, g = lane >> 4;
  int wi0 = ib + (w >> 1) * 64;
  int wj0 = jb + (w & 1) * 32;

  f32x4 acc1[4][2], acc2[4][2];
#pragma unroll
  for (int m = 0; m < 4; ++m)
#pragma unroll
    for (int n = 0; n < 2; ++n) {
      acc1[m][n] = (f32x4){0.f, 0.f, 0.f, 0.f};
      acc2[m][n] = (f32x4){0.f, 0.f, 0.f, 0.f};
    }

  for (int k0 = 0; k0 < D; k0 += 32) {
    bf16x8 aF[4], a2F[4], bF[2], b2F[2];
#pragma unroll
    for (int m = 0; m < 4; ++m) {
      aF[m] = *(const bf16x8*)(QR + (size_t)(wi0 + m * 16 + c) * D + k0 + g * 8);
      a2F[m] = *(const bf16x8*)(Qs + (size_t)(wi0 + m * 16 + c) * D + k0 + g * 8);
    }
#pragma unroll
    for (int n = 0; n < 2; ++n) {
      bF[n] = *(const bf16x8*)(KR + (size_t)(wj0 + n * 16 + c) * D + k0 + g * 8);
      b2F[n] = *(const bf16x8*)(Kb + (size_t)(wj0 + n * 16 + c) * D + k0 + g * 8);
    }
#pragma unroll
    for (int m = 0; m < 4; ++m)
#pragma unroll
      for (int n = 0; n < 2; ++n) {
        acc1[m][n] = MFMA(aF[m], bF[n], acc1[m][n]);
        acc2[m][n] = MFMA(a2F[m], b2F[n], acc2[m][n]);
      }
  }

#pragma unroll
  for (int m = 0; m < 4; ++m)
#pragma unroll
    for (int n = 0; n < 2; ++n) {
      int j = wj0 + n * 16 + c;
      f32x4 o;
#pragma unroll
      for (int r = 0; r < 4; ++r) o[r] = (acc1[m][n][r] - acc2[m][n][r]) * 0.0625f;
      avg4[(size_t)(((wi0 + m * 16) >> 2) + g) * L + j] = o;
    }
}

// ---------------------------------------------------------------- single-pass flash, KV-split
// grid (L/64, NH, SPLIT). Unconditional double-buffered staging; wave-uniform
// compute-side tile skip (ids sorted). LDS 40960.
__global__ __launch_bounds__(256) void flash3_kernel(
    const short* __restrict__ Qs, const short* __restrict__ Kb,
    const short* __restrict__ QR, const short* __restrict__ KR,
    const short* __restrict__ Vt, const f32x4* __restrict__ avg4,
    const int* __restrict__ ids, float* __restrict__ m_part,
    float* __restrict__ l_part, float* __restrict__ acc_part) {
  int h = blockIdx.y, sp = blockIdx.z;
  int w = threadIdx.x >> 6, lane = threadIdx.x & 63;
  int c = lane & 15, g = lane >> 4;
  int i0 = blockIdx.x * 64 + w * 16;
  int hk = h * 64;

  __shared__ short kb_lds[2][64 * 64];
  __shared__ short kr_lds[2][64 * 64];
  __shared__ short plds[4][16][64];  // [wave][row][col ^ ((row&7)<<3)]

  int srow = lane >> 3;
  int sxor = (lane & 7) ^ srow;
  int r0a = w * 16, r0b = w * 16 + 8;

  bf16x8 qA[2], qrA[2];
  {
    const short* qp = Qs + (size_t)(i0 + c) * D + hk + g * 8;
    const short* qrp = QR + (size_t)(i0 + c) * D + hk + g * 8;
    qA[0] = *(const bf16x8*)qp;   qA[1] = *(const bf16x8*)(qp + 32);
    qrA[0] = *(const bf16x8*)qrp; qrA[1] = *(const bf16x8*)(qrp + 32);
  }

  int idi[4];
  float mrun[4], lsum[4];
  f32x4 acc[4];
#pragma unroll
  for (int r = 0; r < 4; ++r) {
    idi[r] = ids[i0 + g * 4 + r];
    mrun[r] = -3.0e38f;
    lsum[r] = 0.f;
  }
#pragma unroll
  for (int n = 0; n < 4; ++n) acc[n] = (f32x4){0.f, 0.f, 0.f, 0.f};

  // wave-uniform i-segment test (ids sorted)
  int ifirst = __shfl(idi[0], 0);
  bool iu = __all((idi[0] == idi[1]) & (idi[1] == idi[2]) & (idi[2] == idi[3]) &
                  (idi[0] == ifirst));

  const f32x4* avrow = avg4 + (size_t)((i0 >> 2) + g) * L;
  int jbase = sp * JCH;
  const int NT = JCH / 64;

  gll16(Kb + (size_t)(jbase + r0a + srow) * D + hk + sxor * 8, &kb_lds[0][r0a * 64]);
  gll16(Kb + (size_t)(jbase + r0b + srow) * D + hk + sxor * 8, &kb_lds[0][r0b * 64]);
  gll16(KR + (size_t)(jbase + r0a + srow) * D + hk + sxor * 8, &kr_lds[0][r0a * 64]);
  gll16(KR + (size_t)(jbase + r0b + srow) * D + hk + sxor * 8, &kr_lds[0][r0b * 64]);

  f32x4 avn[4];
  int idjn[4];
#pragma unroll
  for (int sub = 0; sub < 4; ++sub) {
    avn[sub] = avrow[jbase + sub * 16 + c];
    idjn[sub] = ids[jbase + sub * 16 + c];
  }
  __syncthreads();

  int cur = 0;
  for (int jt = 0; jt < NT; ++jt) {
    int jb = jbase + jt * 64;

    if (jt + 1 < NT) {
      int jn = jb + 64;
      short* kd = &kb_lds[cur ^ 1][0];
      short* rd = &kr_lds[cur ^ 1][0];
      gll16(Kb + (size_t)(jn + r0a + srow) * D + hk + sxor * 8, kd + r0a * 64);
      gll16(Kb + (size_t)(jn + r0b + srow) * D + hk + sxor * 8, kd + r0b * 64);
      gll16(KR + (size_t)(jn + r0a + srow) * D + hk + sxor * 8, rd + r0a * 64);
      gll16(KR + (size_t)(jn + r0b + srow) * D + hk + sxor * 8, rd + r0b * 64);
    }

    bf16x8 vf0[4], vf1[4];
#pragma unroll
    for (int n = 0; n < 4; ++n) {
      const short* vp = Vt + (size_t)(hk + n * 16 + c) * L + jb + g * 8;
      vf0[n] = *(const bf16x8*)vp;
      vf1[n] = *(const bf16x8*)(vp + 32);
    }

    f32x4 av[4];
    int idj[4];
#pragma unroll
    for (int sub = 0; sub < 4; ++sub) { av[sub] = avn[sub]; idj[sub] = idjn[sub]; }
    if (jt + 1 < NT) {
#pragma unroll
      for (int sub = 0; sub < 4; ++sub) {
        avn[sub] = avrow[jb + 64 + sub * 16 + c];
        idjn[sub] = ids[jb + 64 + sub * 16 + c];
      }
    }

    // wave-uniform j-segment test
    int jfirst = __shfl(idj[0], 0);
    bool ju = __all((idj[0] == idj[1]) & (idj[1] == idj[2]) & (idj[2] == idj[3]) &
                    (idj[0] == jfirst));

    const short* kbb = &kb_lds[cur][c * 64];
    const short* krb = &kr_lds[cur][c * 64];
    int co0 = (g ^ (c & 7)) * 8;
    int co1 = ((4 + g) ^ (c & 7)) * 8;

    float t[4][4];
    if (iu && ju && ifirst == jfirst) {
      // pure diagonal: rpe only
#pragma unroll
      for (int sub = 0; sub < 4; ++sub) {
        bf16x8 kr0 = *(const bf16x8*)(krb + sub * 1024 + co0);
        bf16x8 kr1 = *(const bf16x8*)(krb + sub * 1024 + co1);
        f32x4 z = (f32x4){0.f, 0.f, 0.f, 0.f};
        f32x4 rp = MFMA(qrA[1], kr1, MFMA(qrA[0], kr0, z));
#pragma unroll
        for (int r = 0; r < 4; ++r) t[sub][r] = rp[r];
      }
    } else if (iu && ju) {
      // pure off-diagonal: raw + avg only
#pragma unroll
      for (int sub = 0; sub < 4; ++sub) {
        bf16x8 k0 = *(const bf16x8*)(kbb + sub * 1024 + co0);
        bf16x8 k1 = *(const bf16x8*)(kbb + sub * 1024 + co1);
        f32x4 z = (f32x4){0.f, 0.f, 0.f, 0.f};
        f32x4 rw = MFMA(qA[1], k1, MFMA(qA[0], k0, z));
#pragma unroll
        for (int r = 0; r < 4; ++r) t[sub][r] = rw[r] + av[sub][r];
      }
    } else {
      // mixed tile: full path
#pragma unroll
      for (int sub = 0; sub < 4; ++sub) {
        bf16x8 k0 = *(const bf16x8*)(kbb + sub * 1024 + co0);
        bf16x8 k1 = *(const bf16x8*)(kbb + sub * 1024 + co1);
        bf16x8 kr0 = *(const bf16x8*)(krb + sub * 1024 + co0);
        bf16x8 kr1 = *(const bf16x8*)(krb + sub * 1024 + co1);
        f32x4 z = (f32x4){0.f, 0.f, 0.f, 0.f};
        f32x4 rw = MFMA(qA[1], k1, MFMA(qA[0], k0, z));
        f32x4 rp = MFMA(qrA[1], kr1, MFMA(qrA[0], kr0, z));
#pragma unroll
        for (int r = 0; r < 4; ++r)
          t[sub][r] = (idi[r] == idj[sub]) ? rp[r] : (rw[r] + av[sub][r]);
      }
    }

    // defer-max
    float tm[4];
#pragma unroll
    for (int r = 0; r < 4; ++r)
      tm[r] = fmaxf(fmaxf(t[0][r], t[1][r]), fmaxf(t[2][r], t[3][r]));
    bool ok = (tm[0] <= mrun[0] + 8.f) && (tm[1] <= mrun[1] + 8.f) &&
              (tm[2] <= mrun[2] + 8.f) && (tm[3] <= mrun[3] + 8.f);
    if (!__all(ok)) {
#pragma unroll
      for (int r = 0; r < 4; ++r) {
        float m2 = tm[r];
#pragma unroll
        for (int d = 1; d < 16; d <<= 1) m2 = fmaxf(m2, __shfl_xor(m2, d));
        float mn = fmaxf(mrun[r], m2);
        float so = exp2f(mrun[r] - mn);
        mrun[r] = mn;
        lsum[r] *= so;
#pragma unroll
        for (int n = 0; n < 4; ++n) acc[n][r] *= so;
      }
    }

    // p = exp2(t - m) -> swizzled plds
#pragma unroll
    for (int sub = 0; sub < 4; ++sub)
#pragma unroll
      for (int r = 0; r < 4; ++r) {
        float p = exp2f(t[sub][r] - mrun[r]);
        lsum[r] += p;
        int prow = g * 4 + r;
        plds[w][prow][(sub * 16 + c) ^ ((prow & 7) << 3)] = f2bf(p);
      }

    // PV with swizzled reads
    {
      int pc0 = (g * 8) ^ ((c & 7) << 3);
      int pc1 = (32 + g * 8) ^ ((c & 7) << 3);
      bf16x8 pa = *(const bf16x8*)(&plds[w][c][pc0]);
#pragma unroll
      for (int n = 0; n < 4; ++n) acc[n] = MFMA(pa, vf0[n], acc[n]);
      bf16x8 pb = *(const bf16x8*)(&plds[w][c][pc1]);
#pragma unroll
      for (int n = 0; n < 4; ++n) acc[n] = MFMA(pb, vf1[n], acc[n]);
    }

    __syncthreads();
    cur ^= 1;
  }

#pragma unroll
  for (int r = 0; r < 4; ++r) {
#pragma unroll
    for (int d = 1; d < 16; d <<= 1) lsum[r] += __shfl_xor(lsum[r], d);
  }
  size_t sb = (size_t)(sp * NH + h) * L;
  if (c == 0) {
#pragma unroll
    for (int r = 0; r < 4; ++r) {
      m_part[sb + i0 + g * 4 + r] = mrun[r];
      l_part[sb + i0 + g * 4 + r] = lsum[r];
    }
  }
#pragma unroll
  for (int n = 0; n < 4; ++n)
#pragma unroll
    for (int r = 0; r < 4; ++r)
      acc_part[(sb + i0 + g * 4 + r) * HD + n * 16 + c] = acc[n][r];
}

// ---------------------------------------------------------------- merge partials
__global__ void merge_kernel(const float* __restrict__ m_part,
                             const float* __restrict__ l_part,
                             const float* __restrict__ acc_part,
                             float* __restrict__ mfin, float* __restrict__ lfin,
                             short* __restrict__ attn_bf) {
  int idx = blockIdx.x * 256 + threadIdx.x;  // NH*L*HD
  int d = idx & (HD - 1);
  int hi = idx >> 6;          // h*L + i
  int i = hi & (L - 1), h = hi >> 11;
  float m4 = -3.0e38f;
#pragma unroll
  for (int s = 0; s < SPLIT; ++s)
    m4 = fmaxf(m4, m_part[(size_t)(s * NH + h) * L + i]);
  float l = 0.f, o = 0.f;
#pragma unroll
  for (int s = 0; s < SPLIT; ++s) {
    size_t sb = (size_t)(s * NH + h) * L + i;
    float e = exp2f(m_part[sb] - m4);
    l += l_part[sb] * e;
    o += acc_part[sb * HD + d] * e;
  }
  attn_bf[(size_t)i * D + h * HD + d] = f2bf(o / l);
  if (d == 0) { mfin[h * L + i] = m4; lfin[h * L + i] = l; }
}

// ---------------------------------------------------------------- probs mean + out proj (fused launch)
// grid 1536 blocks 1D: [0,1024) pavg body (32x32 j,i blocks); [1024,1536) outproj.
__global__ __launch_bounds__(256) void pavgout_kernel(
    const short* __restrict__ Qs, const short* __restrict__ Kb,
    const short* __restrict__ QR, const short* __restrict__ KR,
    const f32x4* __restrict__ avg4, const int* __restrict__ ids,
    const float* __restrict__ m_ws, const float* __restrict__ l_ws,
    float* __restrict__ out1,
    const short* __restrict__ A, const short* __restrict__ W,
    const float* __restrict__ bias, float* __restrict__ out0) {
  __shared__ short kb_lds[2][64 * 64];
  __shared__ short kr_lds[2][64 * 64];
  __shared__ float mS[NH][64], lS[NH][64];

  int bid = blockIdx.x;
  int w = threadIdx.x >> 6, lane = threadIdx.x & 63;
  int c = lane & 15, g = lane >> 4;

  if (bid >= 1024) {
    // ---------------- out proj body (64x64 tile) ----------------
    int idx = bid - 1024;
    int wj0 = (idx & 15) * 64 + (w & 1) * 32;
    int wi0 = (idx >> 4) * 64 + (w >> 1) * 32;

    f32x4 acc[2][2];
#pragma unroll
    for (int m = 0; m < 2; ++m)
#pragma unroll
      for (int n = 0; n < 2; ++n) acc[m][n] = (f32x4){0.f, 0.f, 0.f, 0.f};

    for (int k0 = 0; k0 < D; k0 += 32) {
      bf16x8 aF[2], bF[2];
#pragma unroll
      for (int m = 0; m < 2; ++m)
        aF[m] = *(const bf16x8*)(A + (size_t)(wi0 + m * 16 + c) * D + k0 + g * 8);
#pragma unroll
      for (int n = 0; n < 2; ++n)
        bF[n] = *(const bf16x8*)(W + (size_t)(wj0 + n * 16 + c) * D + k0 + g * 8);
#pragma unroll
      for (int m = 0; m < 2; ++m)
#pragma unroll
        for (int n = 0; n < 2; ++n) acc[m][n] = MFMA(aF[m], bF[n], acc[m][n]);
    }

#pragma unroll
    for (int m = 0; m < 2; ++m)
#pragma unroll
      for (int n = 0; n < 2; ++n)
#pragma unroll
        for (int r = 0; r < 4; ++r) {
          int i = wi0 + m * 16 + g * 4 + r;
          int col = wj0 + n * 16 + c;
          out0[(size_t)i * D + col] = acc[m][n][r] + bias[col];
        }
    return;
  }

  // ---------------- pavg body ----------------
  int j0 = (bid & 31) * 64;
  int iblk = (bid >> 5) * 64;
  int i0 = iblk + w * 16;

  int srow = lane >> 3;
  int sxor = (lane & 7) ^ srow;
  int r0a = w * 16, r0b = w * 16 + 8;

  // block-constant segment mode (wave-uniform scalar loads; ids sorted)
  int si0 = ids[iblk], si1 = ids[iblk + 63];
  int sj0 = ids[j0], sj1 = ids[j0 + 63];
  int mode = (si0 == si1 && sj0 == sj1) ? ((si0 == sj0) ? 0 : 1) : 2;

  for (int idx = threadIdx.x; idx < NH * 64; idx += 256) {
    int hh = idx >> 6, rr = idx & 63;
    mS[hh][rr] = m_ws[hh * L + iblk + rr];
    lS[hh][rr] = 1.0f / l_ws[hh * L + iblk + rr];
  }

  // stage head 0 (skip the unneeded array when mode is uniform)
  if (mode != 0) {
    gll16(Kb + (size_t)(j0 + r0a + srow) * D + sxor * 8, &kb_lds[0][r0a * 64]);
    gll16(Kb + (size_t)(j0 + r0b + srow) * D + sxor * 8, &kb_lds[0][r0b * 64]);
  }
  if (mode != 1) {
    gll16(KR + (size_t)(j0 + r0a + srow) * D + sxor * 8, &kr_lds[0][r0a * 64]);
    gll16(KR + (size_t)(j0 + r0b + srow) * D + sxor * 8, &kr_lds[0][r0b * 64]);
  }

  int idi[4], idj[4];
  f32x4 av[4];
  {
    const f32x4* avrow = avg4 + (size_t)((i0 >> 2) + g) * L;
#pragma unroll
    for (int sub = 0; sub < 4; ++sub) {
      av[sub] = avrow[j0 + sub * 16 + c];
      idj[sub] = ids[j0 + sub * 16 + c];
    }
#pragma unroll
    for (int r = 0; r < 4; ++r) idi[r] = ids[i0 + g * 4 + r];
  }

  f32x4 psum[4];
#pragma unroll
  for (int sub = 0; sub < 4; ++sub) psum[sub] = (f32x4){0.f, 0.f, 0.f, 0.f};

  const short* qbase = Qs + (size_t)(i0 + c) * D + g * 8;
  const short* qrbase = QR + (size_t)(i0 + c) * D + g * 8;

  bf16x8 nq0, nq1, nqr0, nqr1;
  if (mode != 0) { nq0 = *(const bf16x8*)qbase; nq1 = *(const bf16x8*)(qbase + 32); }
  if (mode != 1) { nqr0 = *(const bf16x8*)qrbase; nqr1 = *(const bf16x8*)(qrbase + 32); }

  __syncthreads();

  int cur = 0;
#pragma unroll 1
  for (int hh = 0; hh < NH; ++hh) {
    if (hh + 1 < NH) {
      int hkn = (hh + 1) * 64;
      short* kd = &kb_lds[cur ^ 1][0];
      short* rd = &kr_lds[cur ^ 1][0];
      if (mode != 0) {
        gll16(Kb + (size_t)(j0 + r0a + srow) * D + hkn + sxor * 8, kd + r0a * 64);
        gll16(Kb + (size_t)(j0 + r0b + srow) * D + hkn + sxor * 8, kd + r0b * 64);
      }
      if (mode != 1) {
        gll16(KR + (size_t)(j0 + r0a + srow) * D + hkn + sxor * 8, rd + r0a * 64);
        gll16(KR + (size_t)(j0 + r0b + srow) * D + hkn + sxor * 8, rd + r0b * 64);
      }
    }

    bf16x8 q0 = nq0, q1 = nq1, qr0 = nqr0, qr1 = nqr1;
    if (hh + 1 < NH) {
      int hkn = (hh + 1) * 64;
      if (mode != 0) {
        nq0 = *(const bf16x8*)(qbase + hkn);
        nq1 = *(const bf16x8*)(qbase + hkn + 32);
      }
      if (mode != 1) {
        nqr0 = *(const bf16x8*)(qrbase + hkn);
        nqr1 = *(const bf16x8*)(qrbase + hkn + 32);
      }
    }

    const short* kbb = &kb_lds[cur][c * 64];
    const short* krb = &kr_lds[cur][c * 64];
    int co0 = (g ^ (c & 7)) * 8;
    int co1 = ((4 + g) ^ (c & 7)) * 8;

    f32x4 m4 = *(const f32x4*)(&mS[hh][w * 16 + g * 4]);
    f32x4 l4 = *(const f32x4*)(&lS[hh][w * 16 + g * 4]);

    if (mode == 0) {
#pragma unroll
      for (int sub = 0; sub < 4; ++sub) {
        bf16x8 kr0 = *(const bf16x8*)(krb + sub * 1024 + co0);
        bf16x8 kr1 = *(const bf16x8*)(krb + sub * 1024 + co1);
        f32x4 z = (f32x4){0.f, 0.f, 0.f, 0.f};
        f32x4 rp = MFMA(qr1, kr1, MFMA(qr0, kr0, z));
#pragma unroll
        for (int r = 0; r < 4; ++r)
          psum[sub][r] += exp2f(rp[r] - m4[r]) * l4[r];
      }
    } else if (mode == 1) {
#pragma unroll
      for (int sub = 0; sub < 4; ++sub) {
        bf16x8 k0 = *(const bf16x8*)(kbb + sub * 1024 + co0);
        bf16x8 k1 = *(const bf16x8*)(kbb + sub * 1024 + co1);
        f32x4 z = (f32x4){0.f, 0.f, 0.f, 0.f};
        f32x4 rw = MFMA(q1, k1, MFMA(q0, k0, z));
#pragma unroll
        for (int r = 0; r < 4; ++r)
          psum[sub][r] += exp2f(rw[r] + av[sub][r] - m4[r]) * l4[r];
      }
    } else {
#pragma unroll
      for (int sub = 0; sub < 4; ++sub) {
        bf16x8 k0 = *(const bf16x8*)(kbb + sub * 1024 + co0);
        bf16x8 k1 = *(const bf16x8*)(kbb + sub * 1024 + co1);
        bf16x8 kr0 = *(const bf16x8*)(krb + sub * 1024 + co0);
        bf16x8 kr1 = *(const bf16x8*)(krb + sub * 1024 + co1);
        f32x4 z = (f32x4){0.f, 0.f, 0.f, 0.f};
        f32x4 rw = MFMA(q1, k1, MFMA(q0, k0, z));
        f32x4 rp = MFMA(qr1, kr1, MFMA(qr0, kr0, z));
#pragma unroll
        for (int r = 0; r < 4; ++r) {
          float s = (idi[r] == idj[sub]) ? rp[r] : (rw[r] + av[sub][r]);
          psum[sub][r] += exp2f(s - m4[r]) * l4[r];
        }
      }
    }

    __syncthreads();
    cur ^= 1;
  }

#pragma unroll
  for (int sub = 0; sub < 4; ++sub)
#pragma unroll
    for (int r = 0; r < 4; ++r)
      out1[(size_t)(i0 + g * 4 + r) * L + j0 + sub * 16 + c] = psum[sub][r] * 0.0625f;
}

// ---------------------------------------------------------------- launch
extern "C" void kernel_launch(void* const* d_in, const int* in_sizes, int n_in,
                              void* d_out, int out_size, void* d_ws, size_t ws_size,
                              hipStream_t stream) {
  const float* query = (const float*)d_in[0];
  const int* ids = (const int*)d_in[1];
  const float* wq = (const float*)d_in[2];
  const float* bq = (const float*)d_in[3];
  const float* wk = (const float*)d_in[4];
  const float* bk = (const float*)d_in[5];
  const float* wv = (const float*)d_in[6];
  const float* bv = (const float*)d_in[7];
  const float* wo = (const float*)d_in[8];
  const float* bo = (const float*)d_in[9];

  char* p = (char*)d_ws;
  auto carve = [&](size_t bytes) {
    char* r = p;
    p += (bytes + 255) & ~(size_t)255;
    return r;
  };
  short* Xbf = (short*)carve((size_t)L * D * 2);
  short* Wqb = (short*)carve((size_t)D * D * 2);
  short* Wkb = (short*)carve((size_t)D * D * 2);
  short* Wvb = (short*)carve((size_t)D * D * 2);
  short* Wob = (short*)carve((size_t)D * D * 2);
  short* Qs = (short*)carve((size_t)L * D * 2);
  short* QRb = (short*)carve((size_t)L * D * 2);
  short* Kbb = (short*)carve((size_t)L * D * 2);
  short* KRb = (short*)carve((size_t)L * D * 2);
  short* Vt = (short*)carve((size_t)L * D * 2);
  f32x4* avg4 = (f32x4*)carve((size_t)L * L * 4);
  float* m_ws = (float*)carve((size_t)NH * L * 4);
  float* l_ws = (float*)carve((size_t)NH * L * 4);
  short* attn_bf = (short*)carve((size_t)L * D * 2);
  float* costab = (float*)carve((size_t)L * 32 * 4);
  float* sintab = (float*)carve((size_t)L * 32 * 4);
  float* m_part = (float*)carve((size_t)SPLIT * NH * L * 4);
  float* l_part = (float*)carve((size_t)SPLIT * NH * L * 4);
  float* acc_part = (float*)carve((size_t)SPLIT * NH * L * HD * 4);

  float* out0 = (float*)d_out;                  // (L, 1, D)
  float* out1 = out0 + (size_t)L * D;           // (1, L, L)

  prep_kernel<<<(65536 + L * D / 4 + 4 * (D * D / 4)) / 256, 256, 0, stream>>>(
      query, wq, wk, wv, wo, costab, sintab, Xbf, Wqb, Wkb, Wvb, Wob);

  proj3_kernel<<<dim3(D / 64, L / 128, 3), 256, 0, stream>>>(
      Xbf, Wqb, Wkb, Wvb, bq, bk, bv, costab, sintab, Qs, QRb, Kbb, KRb, Vt);

  avg_kernel<<<dim3(L / 64, L / 128), 256, 0, stream>>>(QRb, KRb, Qs, Kbb, ids, avg4);

  flash3_kernel<<<dim3(L / 64, NH, SPLIT), 256, 0, stream>>>(
      Qs, Kbb, QRb, KRb, Vt, avg4, ids, m_part, l_part, acc_part);

  merge_kernel<<<(NH * L * HD) / 256, 256, 0, stream>>>(m_part, l_part, acc_part,
                                                        m_ws, l_ws, attn_bf);

  pavgout_kernel<<<1536, 256, 0, stream>>>(Qs, Kbb, QRb, KRb, avg4, ids,
                                           m_ws, l_ws, out1, attn_bf, Wob, bo, out0);
}